// Round 12
// baseline (194.570 us; speedup 1.0000x reference)
//
#include <hip/hip_runtime.h>

#define BB 4
#define NN 16384
#define MM 8192      // N/2
#define FD 64
#define CHUNK 256
#define QPT 2
#define TPB 256
#define QPB (TPB * QPT)   // 512 queries per block
#define NBOUND 1024       // candidates scanned by the bound pass
#define BINS 128

// d_out float offsets
#define OUT0 0              // valid_pc   (4,8192,3)
#define OUT1 98304          // valid_feats(4,8192,64)
#define OUT2 2195456        // n_idx      (4,8192)
#define OUT3 2228224        // rnds       (1,16384)

// d_ws layout (bytes)
#define CAND_OFF   0
#define CAND_BYTES ((size_t)BB * MM * 16)
#define SCAND_OFF  (CAND_OFF + CAND_BYTES)
#define BOUND_OFF  (SCAND_OFF + CAND_BYTES)
#define BOUND_BYTES ((size_t)BB * MM * 4)
#define SKIDX_OFF  (BOUND_OFF + BOUND_BYTES)
#define SQID_OFF   (SKIDX_OFF + BOUND_BYTES)
#define META_OFF   (SQID_OFF + BOUND_BYTES)
#define META_BYTES ((size_t)16384
#define FIXED_BYTES (META_OFF + 16384)
// meta int indices: khist 0, qhist 512, kcur 1024, qcur 1536, koff 2048(4x129), qoff 2564(4x129)

struct Partial { double m1, m2; };

// ---- HW-verified bit-exact pieces (r7/r10: absmax 0) ----
__device__ __forceinline__ float sumsq3_rn(float x, float y, float z) {
  return __fadd_rn(__fadd_rn(__fmul_rn(x, x), __fmul_rn(y, y)), __fmul_rn(z, z));
}
__device__ __forceinline__ float dist2_rn(float qx, float qy, float qz, float q2,
                                          float4 t) {
  float cross2 = __fmaf_rn(qz, t.z, __fmaf_rn(qy, t.y, __fmul_rn(qx, t.x)));
  return __fadd_rn(__fsub_rn(q2, cross2), t.w);
}
__device__ __forceinline__ double mkkey(float d2, int k) {
  return __hiloint2double(__float_as_int(d2), k);
}
#define KEY_INIT __hiloint2double(0x7F800000, 0x7FFFFFFF)

// One monotone clamped bin map used by hist/scatter/window alike (2x-space).
__device__ __forceinline__ int bin128(float v2x) {
  float f = floorf((v2x + 12.0f) * (BINS / 24.0f));
  f = fmaxf(0.0f, fminf((float)(BINS - 1), f));
  return (int)f;
}

__global__ __launch_bounds__(256) void gather_kernel(
    const float* __restrict__ pc, const float* __restrict__ feats,
    const int* __restrict__ perm, float* __restrict__ out,
    float4* __restrict__ cand) {
  int idx = blockIdx.x * 256 + threadIdx.x;
  const int F4_TOT = BB * MM * FD / 4;
  const int PTS    = BB * MM;
  if (idx < F4_TOT) {
    int f4 = idx & 15;
    int r  = (idx >> 4) & (MM - 1);
    int b  = idx >> 17;
    int vi = perm[r];
    const float4* src = (const float4*)(feats + ((b * NN + vi) << 6));
    float4* dst = (float4*)(out + OUT1) + idx;
    *dst = src[f4];
  } else if (idx < F4_TOT + PTS) {
    int k = idx - F4_TOT;
    int r = k & (MM - 1);
    int b = k >> 13;
    int vi = perm[r];
    const float* src = pc + (b * NN + vi) * 3;
    float px = src[0], py = src[1], pz = src[2];
    float* dst = out + OUT0 + k * 3;
    dst[0] = px; dst[1] = py; dst[2] = pz;
    cand[k] = make_float4(px + px, py + py, pz + pz, sumsq3_rn(px, py, pz));
  } else if (idx < F4_TOT + PTS + NN) {
    int k = idx - F4_TOT - PTS;
    out[OUT3 + k] = (float)perm[k];
  }
}

// Histogram candidates (by cand.x = 2px) and queries (by 2qx) into 128 bins.
__global__ __launch_bounds__(256) void hist_kernel(
    const float* __restrict__ pc, const int* __restrict__ perm,
    const float4* __restrict__ cand, int* __restrict__ meta) {
  int idx = blockIdx.x * 256 + threadIdx.x;   // 0..65535
  if (idx < BB * MM) {
    int b = idx >> 13;
    atomicAdd(&meta[0 + b * BINS + bin128(cand[idx].x)], 1);
  } else if (idx < 2 * BB * MM) {
    int qid = idx - BB * MM;
    int b = qid >> 13, j = qid & (MM - 1);
    int qi = perm[MM + j];
    float qx = pc[(b * NN + qi) * 3];
    atomicAdd(&meta[512 + b * BINS + bin128(qx + qx)], 1);
  }
}

__global__ void prefix_kernel(int* __restrict__ meta) {
  int t = threadIdx.x;
  if (t < 4) {
    const int* h = meta + 0 + t * BINS;
    int* o = meta + 2048 + t * 129;
    int acc = 0;
    for (int i = 0; i < BINS; ++i) { o[i] = acc; acc += h[i]; }
    o[BINS] = acc;
  } else if (t < 8) {
    int b = t - 4;
    const int* h = meta + 512 + b * BINS;
    int* o = meta + 2564 + b * 129;
    int acc = 0;
    for (int i = 0; i < BINS; ++i) { o[i] = acc; acc += h[i]; }
    o[BINS] = acc;
  }
}

// Counting-sort scatter. Within-bin order is nondeterministic (atomics) but the
// final result is invariant: keys are totally ordered and carry true indices.
__global__ __launch_bounds__(256) void scatter_kernel(
    const float* __restrict__ pc, const int* __restrict__ perm,
    const float4* __restrict__ cand, int* __restrict__ meta,
    float4* __restrict__ scand, int* __restrict__ skidx,
    int* __restrict__ sqid) {
  int idx = blockIdx.x * 256 + threadIdx.x;
  if (idx < BB * MM) {
    int b = idx >> 13;
    float4 cv = cand[idx];
    int bin = bin128(cv.x);
    int pos = meta[2048 + b * 129 + bin] + atomicAdd(&meta[1024 + b * BINS + bin], 1);
    int g = (b << 13) + pos;
    scand[g] = cv;
    skidx[g] = idx & (MM - 1);
  } else if (idx < 2 * BB * MM) {
    int qid = idx - BB * MM;
    int b = qid >> 13, j = qid & (MM - 1);
    int qi = perm[MM + j];
    float qx = pc[(b * NN + qi) * 3];
    int bin = bin128(qx + qx);
    int pos = meta[2564 + b * 129 + bin] + atomicAdd(&meta[1536 + b * BINS + bin], 1);
    sqid[(b << 13) + pos] = j;
  }
}

// Upper bound on final m2 VALUE: top-2 values over cand[0:NBOUND), 8 thr/query.
__global__ __launch_bounds__(256) void bound_kernel(
    const float* __restrict__ pc, const int* __restrict__ perm,
    const float4* __restrict__ cand, float* __restrict__ bound2) {
  #pragma clang fp contract(off)
  int gid = blockIdx.x * 256 + threadIdx.x;   // 0..262143
  int q = gid >> 3, t = gid & 7;
  int b = q >> 13, j = q & (MM - 1);
  int qi = perm[MM + j];
  const float* qp = pc + (b * NN + qi) * 3;
  float qx = qp[0], qy = qp[1], qz = qp[2];
  float q2 = sumsq3_rn(qx, qy, qz);
  float m1 = 3.4e38f, m2 = 3.4e38f;
  const float4* cb = cand + (b << 13) + t * (NBOUND / 8);
  #pragma unroll 4
  for (int i = 0; i < NBOUND / 8; ++i) {
    float d2 = dist2_rn(qx, qy, qz, q2, cb[i]);
    m2 = __builtin_amdgcn_fmed3f(d2, m1, m2);
    m1 = fminf(d2, m1);
  }
  // merge (m1,m2) value-pairs across the 8 lanes of this query
  #pragma unroll
  for (int mask = 1; mask < 8; mask <<= 1) {
    float o1 = __shfl_xor(m1, mask);
    float o2 = __shfl_xor(m2, mask);
    float n1 = fminf(m1, o1);
    float n2 = fminf(fmaxf(m1, o1), fminf(m2, o2));
    m1 = n1; m2 = n2;
  }
  if (t == 0) bound2[q] = m2;
}

// Main: 512 x-sorted queries per qblock; block-reduced x-window -> bin range;
// branchless f64 packed-key top-2 over the (provable superset) candidate range.
__global__ __launch_bounds__(256) void knn_kernel(
    const float* __restrict__ pc, const int* __restrict__ perm,
    const float4* __restrict__ scand, const int* __restrict__ skidx,
    const int* __restrict__ sqid, const float* __restrict__ bound2,
    const int* __restrict__ meta,
    Partial* __restrict__ part, float* __restrict__ out, int nchunk) {
  #pragma clang fp contract(off)
  int c  = blockIdx.x % nchunk;
  int qb = blockIdx.x / nchunk;       // 0..63
  int b  = qb >> 4;
  int bbase = b << 13;
  int tid = threadIdx.x;

  float qx[QPT], qy[QPT], qz[QPT], q2[QPT];
  int qorig[QPT];
  float myLo = 3.4e38f, myHi = -3.4e38f;
  #pragma unroll
  for (int s = 0; s < QPT; ++s) {
    int slot = (qb & 15) * QPB + tid + s * TPB;
    int j = sqid[bbase + slot];
    qorig[s] = bbase + j;
    int qi = perm[MM + j];
    const float* qp = pc + (b * NN + qi) * 3;
    qx[s] = qp[0]; qy[s] = qp[1]; qz[s] = qp[2];
    q2[s] = sumsq3_rn(qx[s], qy[s], qz[s]);
    float bf = bound2[bbase + j];
    float r2 = 2.0f * sqrtf(bf + 1e-3f) * 1.0001f;   // slack >> rounding err
    myLo = fminf(myLo, (qx[s] + qx[s]) - r2);
    myHi = fmaxf(myHi, (qx[s] + qx[s]) + r2);
  }

  __shared__ float rlo[256], rhi[256];
  rlo[tid] = myLo; rhi[tid] = myHi;
  __syncthreads();
  for (int s2 = 128; s2 > 0; s2 >>= 1) {
    if (tid < s2) {
      rlo[tid] = fminf(rlo[tid], rlo[tid + s2]);
      rhi[tid] = fmaxf(rhi[tid], rhi[tid + s2]);
    }
    __syncthreads();
  }
  float wlo = rlo[0], whi = rhi[0];

  const int* koff = meta + 2048 + b * 129;
  int blo = bin128(wlo), bhi = bin128(whi);
  int plo = bbase + koff[blo];
  int phi = bbase + koff[bhi + 1];
  int len = phi - plo;
  int chunklen = (len + nchunk - 1) / nchunk;
  int start = plo + c * chunklen;
  int end = min(start + chunklen, phi);

  double m1[QPT] = {KEY_INIT, KEY_INIT};
  double m2[QPT] = {KEY_INIT, KEY_INIT};

  __shared__ float4 tile[CHUNK];
  __shared__ int   tidxs[CHUNK];

  for (int t0 = start; t0 < end; t0 += CHUNK) {
    __syncthreads();
    int pos = min(t0 + tid, phi - 1);    // clamp: stay in this batch's region
    tile[tid]  = scand[pos];
    tidxs[tid] = skidx[pos];
    __syncthreads();
    int kmax = min(CHUNK, end - t0);
    #pragma unroll 4
    for (int k = 0; k < kmax; ++k) {
      float4 t = tile[k];
      int ki = tidxs[k];
      #pragma unroll
      for (int s = 0; s < QPT; ++s) {
        float d2 = dist2_rn(qx[s], qy[s], qz[s], q2[s], t);
        double key = mkkey(d2, ki);
        m2[s] = fmin(fmax(key, m1[s]), m2[s]);
        m1[s] = fmin(key, m1[s]);
      }
    }
  }

  #pragma unroll
  for (int s = 0; s < QPT; ++s) {
    if (part != nullptr) {
      Partial pr; pr.m1 = m1[s]; pr.m2 = m2[s];
      part[qorig[s] * nchunk + c] = pr;
    } else {
      out[OUT2 + qorig[s]] = (float)__double2loint(m2[s]);
    }
  }
}

__global__ __launch_bounds__(256) void knn_merge_kernel(
    const Partial* __restrict__ part, float* __restrict__ out, int nchunk) {
  int q = blockIdx.x * 256 + threadIdx.x;
  double m1 = KEY_INIT, m2 = KEY_INIT;
  for (int c = 0; c < nchunk; ++c) {
    Partial p = part[q * nchunk + c];
    m2 = fmin(fmax(p.m1, m1), m2);
    m1 = fmin(p.m1, m1);
    m2 = fmin(fmax(p.m2, m1), m2);
    m1 = fmin(p.m2, m1);
  }
  out[OUT2 + q] = (float)__double2loint(m2);
}

extern "C" void kernel_launch(void* const* d_in, const int* in_sizes, int n_in,
                              void* d_out, int out_size, void* d_ws, size_t ws_size,
                              hipStream_t stream) {
  const float* pc    = (const float*)d_in[0];
  const float* feats = (const float*)d_in[1];
  const int*   perm  = (const int*)d_in[2];
  float* out = (float*)d_out;

  char* ws = (char*)d_ws;
  float4* cand   = (float4*)(ws + CAND_OFF);
  float4* scand  = (float4*)(ws + SCAND_OFF);
  float*  bound2 = (float*)(ws + BOUND_OFF);
  int*    skidx  = (int*)(ws + SKIDX_OFF);
  int*    sqid   = (int*)(ws + SQID_OFF);
  int*    meta   = (int*)(ws + META_OFF);
  char*   rest   = ws + FIXED_BYTES;
  size_t  avail  = ws_size > FIXED_BYTES ? ws_size - FIXED_BYTES : 0;

  // zero hist + scatter counters (khist,qhist,kcur,qcur = first 2048 ints)
  hipMemsetAsync(meta, 0, 2048 * sizeof(int), stream);

  gather_kernel<<<2240, 256, 0, stream>>>(pc, feats, perm, out, cand);
  hist_kernel<<<256, 256, 0, stream>>>(pc, perm, cand, meta);
  prefix_kernel<<<1, 256, 0, stream>>>(meta);
  scatter_kernel<<<256, 256, 0, stream>>>(pc, perm, cand, meta, scand, skidx, sqid);
  bound_kernel<<<1024, 256, 0, stream>>>(pc, perm, cand, bound2);

  int nchunk = 1;
  if      (avail >= (size_t)BB * MM * 32 * sizeof(Partial)) nchunk = 32;
  else if (avail >= (size_t)BB * MM * 16 * sizeof(Partial)) nchunk = 16;
  else if (avail >= (size_t)BB * MM * 8  * sizeof(Partial)) nchunk = 8;
  else if (avail >= (size_t)BB * MM * 4  * sizeof(Partial)) nchunk = 4;
  else if (avail >= (size_t)BB * MM * 2  * sizeof(Partial)) nchunk = 2;

  int qblocks = BB * MM / QPB;   // 64
  if (nchunk > 1) {
    Partial* part = (Partial*)rest;
    knn_kernel<<<qblocks * nchunk, TPB, 0, stream>>>(pc, perm, scand, skidx, sqid,
                                                     bound2, meta, part, out, nchunk);
    knn_merge_kernel<<<BB * MM / 256, 256, 0, stream>>>(part, out, nchunk);
  } else {
    knn_kernel<<<qblocks, TPB, 0, stream>>>(pc, perm, scand, skidx, sqid,
                                            bound2, meta, nullptr, out, 1);
  }
}

// Round 13
// 123.892 us; speedup vs baseline: 1.5705x; 1.5705x over previous
//
#include <hip/hip_runtime.h>

#define BB 4
#define NN 16384
#define MM 8192      // N/2
#define FD 64
#define QPT 2
#define TPB 256
#define NBOUND 1024
#define BINS 128

// d_out float offsets
#define OUT0 0              // valid_pc   (4,8192,3)
#define OUT1 98304          // valid_feats(4,8192,64)
#define OUT2 2195456        // n_idx      (4,8192)
#define OUT3 2228224        // rnds       (1,16384)

// d_ws layout (bytes)
#define CAND_OFF    0
#define CAND_BYTES  ((size_t)BB * MM * 16)
#define SCAND_OFF   (CAND_OFF + CAND_BYTES)
#define BOUND_OFF   (SCAND_OFF + CAND_BYTES)
#define BOUND_BYTES ((size_t)BB * MM * 4)
#define SKIDX_OFF   (BOUND_OFF + BOUND_BYTES)
#define SQID_OFF    (SKIDX_OFF + BOUND_BYTES)
#define META_OFF    (SQID_OFF + BOUND_BYTES)
#define FIXED_BYTES (META_OFF + 16384)
// meta ints: khist 0(4x128), qhist 512, kcur 1024, qcur 1536, koff 2048(4x129), qoff 2564(4x129)

struct Partial { double m1, m2; };

// ---- HW-verified bit-exact pieces (r7/r10/r12: absmax 0) ----
__device__ __forceinline__ float sumsq3_rn(float x, float y, float z) {
  return __fadd_rn(__fadd_rn(__fmul_rn(x, x), __fmul_rn(y, y)), __fmul_rn(z, z));
}
__device__ __forceinline__ float dist2_rn(float qx, float qy, float qz, float q2,
                                          float4 t) {
  float cross2 = __fmaf_rn(qz, t.z, __fmaf_rn(qy, t.y, __fmul_rn(qx, t.x)));
  return __fadd_rn(__fsub_rn(q2, cross2), t.w);
}
__device__ __forceinline__ double mkkey(float d2, int k) {
  return __hiloint2double(__float_as_int(d2), k);
}
#define KEY_INIT __hiloint2double(0x7F800000, 0x7FFFFFFF)

// Monotone clamped bin map in 2x-space (shared by hist/scatter/window).
__device__ __forceinline__ int bin128(float v2x) {
  float f = floorf((v2x + 12.0f) * (BINS / 24.0f));
  f = fmaxf(0.0f, fminf((float)(BINS - 1), f));
  return (int)f;
}

// gather + cand prep + BOTH histograms (candidate px reused in-register).
__global__ __launch_bounds__(256) void gather_kernel(
    const float* __restrict__ pc, const float* __restrict__ feats,
    const int* __restrict__ perm, float* __restrict__ out,
    float4* __restrict__ cand, int* __restrict__ meta) {
  int idx = blockIdx.x * 256 + threadIdx.x;
  const int F4_TOT = BB * MM * FD / 4;
  const int PTS    = BB * MM;
  if (idx < F4_TOT) {
    int f4 = idx & 15;
    int r  = (idx >> 4) & (MM - 1);
    int b  = idx >> 17;
    int vi = perm[r];
    const float4* src = (const float4*)(feats + ((b * NN + vi) << 6));
    float4* dst = (float4*)(out + OUT1) + idx;
    *dst = src[f4];
  } else if (idx < F4_TOT + PTS) {
    int k = idx - F4_TOT;
    int r = k & (MM - 1);
    int b = k >> 13;
    int vi = perm[r];
    const float* src = pc + (b * NN + vi) * 3;
    float px = src[0], py = src[1], pz = src[2];
    float* dst = out + OUT0 + k * 3;
    dst[0] = px; dst[1] = py; dst[2] = pz;
    cand[k] = make_float4(px + px, py + py, pz + pz, sumsq3_rn(px, py, pz));
    atomicAdd(&meta[0 + b * BINS + bin128(px + px)], 1);
  } else if (idx < F4_TOT + PTS + NN) {
    int k = idx - F4_TOT - PTS;
    out[OUT3 + k] = (float)perm[k];
  } else if (idx < F4_TOT + PTS + NN + BB * MM) {
    int qid = idx - F4_TOT - PTS - NN;
    int b = qid >> 13, j = qid & (MM - 1);
    int qi = perm[MM + j];
    float qx = pc[(b * NN + qi) * 3];
    atomicAdd(&meta[512 + b * BINS + bin128(qx + qx)], 1);
  }
}

// 8 scans of 128 bins; loads batched 16-deep into registers (not serial L2).
__global__ void prefix_kernel(int* __restrict__ meta) {
  int t = threadIdx.x;
  if (t < 8) {
    const int* h = meta + (t < 4 ? t * BINS : 512 + (t - 4) * BINS);
    int* o = meta + (t < 4 ? 2048 + t * 129 : 2564 + (t - 4) * 129);
    int acc = 0;
    for (int i0 = 0; i0 < BINS; i0 += 16) {
      int v[16];
      #pragma unroll
      for (int i = 0; i < 16; ++i) v[i] = h[i0 + i];
      #pragma unroll
      for (int i = 0; i < 16; ++i) { o[i0 + i] = acc; acc += v[i]; }
    }
    o[BINS] = acc;
  }
}

// Counting-sort scatter (r12-proven). Within-bin order nondeterministic, but
// final output is invariant: keys are totally ordered and carry true indices.
__global__ __launch_bounds__(256) void scatter_kernel(
    const float* __restrict__ pc, const int* __restrict__ perm,
    const float4* __restrict__ cand, int* __restrict__ meta,
    float4* __restrict__ scand, int* __restrict__ skidx,
    int* __restrict__ sqid) {
  int idx = blockIdx.x * 256 + threadIdx.x;
  if (idx < BB * MM) {
    int b = idx >> 13;
    float4 cv = cand[idx];
    int bin = bin128(cv.x);
    int pos = meta[2048 + b * 129 + bin] + atomicAdd(&meta[1024 + b * BINS + bin], 1);
    int g = (b << 13) + pos;
    scand[g] = cv;
    skidx[g] = idx & (MM - 1);
  } else if (idx < 2 * BB * MM) {
    int qid = idx - BB * MM;
    int b = qid >> 13, j = qid & (MM - 1);
    int qi = perm[MM + j];
    float qx = pc[(b * NN + qi) * 3];
    int bin = bin128(qx + qx);
    int pos = meta[2564 + b * 129 + bin] + atomicAdd(&meta[1536 + b * BINS + bin], 1);
    sqid[(b << 13) + pos] = j;
  }
}

// Upper bound on final m2 VALUE: one wave per query, coalesced candidate reads
// (lane i reads cand[k*64+i]), then 6-step shfl top-2-value merge.
__global__ __launch_bounds__(256) void bound_kernel(
    const float* __restrict__ pc, const int* __restrict__ perm,
    const float4* __restrict__ cand, float* __restrict__ bound2) {
  #pragma clang fp contract(off)
  int wid = threadIdx.x >> 6, lane = threadIdx.x & 63;
  int q = blockIdx.x * 4 + wid;             // 0..B*M-1
  int b = q >> 13, j = q & (MM - 1);
  int qi = perm[MM + j];
  const float* qp = pc + (b * NN + qi) * 3;
  float qx = qp[0], qy = qp[1], qz = qp[2];
  float q2 = sumsq3_rn(qx, qy, qz);
  float m1 = 3.4e38f, m2 = 3.4e38f;
  const float4* cb = cand + (b << 13);
  #pragma unroll 4
  for (int i = 0; i < NBOUND; i += 64) {
    float d2 = dist2_rn(qx, qy, qz, q2, cb[i + lane]);
    m2 = __builtin_amdgcn_fmed3f(d2, m1, m2);
    m1 = fminf(d2, m1);
  }
  #pragma unroll
  for (int mask = 1; mask < 64; mask <<= 1) {
    float o1 = __shfl_xor(m1, mask);
    float o2 = __shfl_xor(m2, mask);
    float n1 = fminf(m1, o1);
    float n2 = fminf(fmaxf(m1, o1), fminf(m2, o2));
    m1 = n1; m2 = n2;
  }
  if (lane == 0) bound2[q] = m2;
}

// Main: each WAVE owns 128 x-sorted queries; wave window via shfl reduce +
// readfirstlane (SGPR-uniform bounds -> scalar-pipe candidate stream).
// Branchless f64 packed-key top-2 over the provable superset range.
__global__ __launch_bounds__(256) void knn_kernel(
    const float* __restrict__ pc, const int* __restrict__ perm,
    const float4* __restrict__ scand, const int* __restrict__ skidx,
    const int* __restrict__ sqid, const float* __restrict__ bound2,
    const int* __restrict__ meta,
    Partial* __restrict__ part, float* __restrict__ out, int nchunk) {
  #pragma clang fp contract(off)
  int c  = blockIdx.x % nchunk;
  int qb = blockIdx.x / nchunk;       // 0..63
  int b  = qb >> 4;
  int bbase = b << 13;
  int wid = threadIdx.x >> 6, lane = threadIdx.x & 63;
  int sbase = (qb & 15) * 512 + wid * 128;   // this wave's sorted-slot base

  float qx[QPT], qy[QPT], qz[QPT], q2[QPT];
  int qorig[QPT];
  float lo = 3.4e38f, hi = -3.4e38f;
  #pragma unroll
  for (int s = 0; s < QPT; ++s) {
    int slot = sbase + lane + s * 64;
    int j = sqid[bbase + slot];
    qorig[s] = bbase + j;
    int qi = perm[MM + j];
    const float* qp = pc + (b * NN + qi) * 3;
    qx[s] = qp[0]; qy[s] = qp[1]; qz[s] = qp[2];
    q2[s] = sumsq3_rn(qx[s], qy[s], qz[s]);
    float bf = bound2[bbase + j];
    // skip only if dx^2 > bf + 1e-3 (absolute slack >> ~5e-6 rounding error)
    float r2 = 2.0f * sqrtf(bf + 1e-3f) * 1.0001f;
    lo = fminf(lo, (qx[s] + qx[s]) - r2);
    hi = fmaxf(hi, (qx[s] + qx[s]) + r2);
  }
  #pragma unroll
  for (int mask = 1; mask < 64; mask <<= 1) {
    lo = fminf(lo, __shfl_xor(lo, mask));
    hi = fmaxf(hi, __shfl_xor(hi, mask));
  }
  const int* koff = meta + 2048 + b * 129;
  int plo = koff[bin128(lo)];
  int phi = koff[bin128(hi) + 1];
  plo = __builtin_amdgcn_readfirstlane(plo);
  phi = __builtin_amdgcn_readfirstlane(phi);
  int chunklen = (phi - plo + nchunk - 1) / nchunk;
  int start = plo + c * chunklen;
  int end = min(start + chunklen, phi);

  double m1[QPT] = {KEY_INIT, KEY_INIT};
  double m2[QPT] = {KEY_INIT, KEY_INIT};
  const float4* cb = scand + bbase;
  const int*    kb = skidx + bbase;

  #pragma unroll 4
  for (int p = start; p < end; ++p) {
    float4 t = cb[p];        // uniform addr -> scalar loads
    int ki = kb[p];
    #pragma unroll
    for (int s = 0; s < QPT; ++s) {
      float d2 = dist2_rn(qx[s], qy[s], qz[s], q2[s], t);
      double key = mkkey(d2, ki);
      m2[s] = fmin(fmax(key, m1[s]), m2[s]);
      m1[s] = fmin(key, m1[s]);
    }
  }

  #pragma unroll
  for (int s = 0; s < QPT; ++s) {
    if (part != nullptr) {
      Partial pr; pr.m1 = m1[s]; pr.m2 = m2[s];
      part[qorig[s] * nchunk + c] = pr;
    } else {
      out[OUT2 + qorig[s]] = (float)__double2loint(m2[s]);
    }
  }
}

__global__ __launch_bounds__(256) void knn_merge_kernel(
    const Partial* __restrict__ part, float* __restrict__ out, int nchunk) {
  int q = blockIdx.x * 256 + threadIdx.x;
  double m1 = KEY_INIT, m2 = KEY_INIT;
  for (int c = 0; c < nchunk; ++c) {
    Partial p = part[q * nchunk + c];
    m2 = fmin(fmax(p.m1, m1), m2);
    m1 = fmin(p.m1, m1);
    m2 = fmin(fmax(p.m2, m1), m2);
    m1 = fmin(p.m2, m1);
  }
  out[OUT2 + q] = (float)__double2loint(m2);
}

extern "C" void kernel_launch(void* const* d_in, const int* in_sizes, int n_in,
                              void* d_out, int out_size, void* d_ws, size_t ws_size,
                              hipStream_t stream) {
  const float* pc    = (const float*)d_in[0];
  const float* feats = (const float*)d_in[1];
  const int*   perm  = (const int*)d_in[2];
  float* out = (float*)d_out;

  char* ws = (char*)d_ws;
  float4* cand   = (float4*)(ws + CAND_OFF);
  float4* scand  = (float4*)(ws + SCAND_OFF);
  float*  bound2 = (float*)(ws + BOUND_OFF);
  int*    skidx  = (int*)(ws + SKIDX_OFF);
  int*    sqid   = (int*)(ws + SQID_OFF);
  int*    meta   = (int*)(ws + META_OFF);
  char*   rest   = ws + FIXED_BYTES;
  size_t  avail  = ws_size > FIXED_BYTES ? ws_size - FIXED_BYTES : 0;

  hipMemsetAsync(meta, 0, 2048 * sizeof(int), stream);

  // 524288 + 32768 + 16384 + 32768 = 606208 -> 2368 blocks
  gather_kernel<<<2368, 256, 0, stream>>>(pc, feats, perm, out, cand, meta);
  prefix_kernel<<<1, 64, 0, stream>>>(meta);
  scatter_kernel<<<256, 256, 0, stream>>>(pc, perm, cand, meta, scand, skidx, sqid);
  bound_kernel<<<BB * MM / 4, 256, 0, stream>>>(pc, perm, cand, bound2);

  int nchunk = 1;
  if      (avail >= (size_t)BB * MM * 32 * sizeof(Partial)) nchunk = 32;
  else if (avail >= (size_t)BB * MM * 16 * sizeof(Partial)) nchunk = 16;
  else if (avail >= (size_t)BB * MM * 8  * sizeof(Partial)) nchunk = 8;
  else if (avail >= (size_t)BB * MM * 4  * sizeof(Partial)) nchunk = 4;
  else if (avail >= (size_t)BB * MM * 2  * sizeof(Partial)) nchunk = 2;

  int qblocks = 64;
  if (nchunk > 1) {
    Partial* part = (Partial*)rest;
    knn_kernel<<<qblocks * nchunk, TPB, 0, stream>>>(pc, perm, scand, skidx, sqid,
                                                     bound2, meta, part, out, nchunk);
    knn_merge_kernel<<<BB * MM / 256, 256, 0, stream>>>(part, out, nchunk);
  } else {
    knn_kernel<<<qblocks, TPB, 0, stream>>>(pc, perm, scand, skidx, sqid,
                                            bound2, meta, nullptr, out, 1);
  }
}